// Round 16
// baseline (165.546 us; speedup 1.0000x reference)
//
#include <hip/hip_runtime.h>
#include <hip/hip_bf16.h>

// Problem constants
#define TSEQ 2048
#define CDIM 768
#define NHEAD 12
#define DHEAD 64
#define FDIM 3072
#define MROWS 4096   // B*T
#define BH 24        // B*H

typedef __attribute__((ext_vector_type(8))) short short8;
typedef __attribute__((ext_vector_type(4))) float f32x4;

__device__ inline unsigned short f2bf(float f) {
  __hip_bfloat16 h = __float2bfloat16(f);
  return __builtin_bit_cast(unsigned short, h);
}
__device__ inline float bf2f(unsigned short u) {
  unsigned int v = ((unsigned int)u) << 16;
  return __builtin_bit_cast(float, v);
}

// async global->LDS DMA, 16B per lane; LDS dest = wave-uniform base + lane*16
__device__ inline void gload16(const unsigned short* g, unsigned short* l) {
  __builtin_amdgcn_global_load_lds(
      (const __attribute__((address_space(1))) unsigned int*)g,
      (__attribute__((address_space(3))) unsigned int*)l, 16, 0, 0);
}

// ------------- fused prep: weight packs + LN1 in one launch -------------
__global__ __launch_bounds__(256) void prep_all(
    const float* __restrict__ Wq, const float* __restrict__ Wk,
    const float* __restrict__ Wv, const float* __restrict__ Wp,
    const float* __restrict__ W1, const float* __restrict__ W2,
    unsigned short* __restrict__ WqkvT, unsigned short* __restrict__ WpT,
    unsigned short* __restrict__ W1T, unsigned short* __restrict__ W2T,
    const float* __restrict__ x, const float* __restrict__ ln1g,
    const float* __restrict__ ln1b, unsigned short* __restrict__ h1) {
  __shared__ float tile[32][33];
  __shared__ float red[8];
  int b = blockIdx.x;
  if (b >= 6912) {
    // ---- LayerNorm path ----
    int row = b - 6912;
    int tid = threadIdx.x;
    const float* xr = x + (size_t)row * CDIM;
    float v[3];
    float s = 0.f;
#pragma unroll
    for (int i = 0; i < 3; ++i) { v[i] = xr[tid + i * 256]; s += v[i]; }
#pragma unroll
    for (int m = 1; m < 64; m <<= 1) s += __shfl_xor(s, m);
    int w = tid >> 6;
    if ((tid & 63) == 0) red[w] = s;
    __syncthreads();
    float mean = (red[0] + red[1] + red[2] + red[3]) * (1.f / CDIM);
    float vs = 0.f;
#pragma unroll
    for (int i = 0; i < 3; ++i) { float d = v[i] - mean; vs += d * d; }
#pragma unroll
    for (int m = 1; m < 64; m <<= 1) vs += __shfl_xor(vs, m);
    if ((tid & 63) == 0) red[4 + w] = vs;
    __syncthreads();
    float var = (red[4] + red[5] + red[6] + red[7]) * (1.f / CDIM);
    float rstd = rsqrtf(var + 1e-5f);
    unsigned short* orow = h1 + (size_t)row * CDIM;
#pragma unroll
    for (int i = 0; i < 3; ++i) {
      int c = tid + i * 256;
      orow[c] = f2bf((v[i] - mean) * rstd * ln1g[c] + ln1b[c]);
    }
    return;
  }
  int xx = threadIdx.x & 31, y = threadIdx.x >> 5;
  if (b < 1728) {
    int cx = b % 24, dy = (b / 24) % 2, ph = b / 48;
    int proj = ph / NHEAD, h = ph % NHEAD;
    const float* in = (proj == 0 ? Wq : (proj == 1 ? Wk : Wv)) + (size_t)h * CDIM * DHEAD;
    int c0 = cx * 32, d0 = dy * 32;
#pragma unroll
    for (int i = 0; i < 4; ++i)
      tile[y + i * 8][xx] = in[(size_t)(c0 + y + i * 8) * DHEAD + d0 + xx];
    __syncthreads();
#pragma unroll
    for (int i = 0; i < 4; ++i)
      WqkvT[(size_t)(proj * CDIM + h * DHEAD + d0 + y + i * 8) * CDIM + c0 + xx] =
          f2bf(tile[xx][y + i * 8]);
  } else {
    const float* in;
    unsigned short* out;
    int R, C, bx, by;
    if (b < 2304) {
      int b2 = b - 1728;
      in = Wp; out = WpT; R = CDIM; C = CDIM; bx = b2 % 24; by = b2 / 24;
    } else if (b < 4608) {
      int b2 = b - 2304;
      in = W1; out = W1T; R = CDIM; C = FDIM; bx = b2 % 96; by = b2 / 96;
    } else {
      int b2 = b - 4608;
      in = W2; out = W2T; R = FDIM; C = CDIM; bx = b2 % 24; by = b2 / 24;
    }
    int c0 = bx * 32, r0 = by * 32;
#pragma unroll
    for (int i = 0; i < 4; ++i)
      tile[y + i * 8][xx] = in[(size_t)(r0 + y + i * 8) * C + c0 + xx];
    __syncthreads();
#pragma unroll
    for (int i = 0; i < 4; ++i)
      out[(size_t)(c0 + y + i * 8) * R + r0 + xx] = f2bf(tile[xx][y + i * 8]);
  }
}

// ------------- fused proj split-K reduce + LN2 -------------
// x1 = x + sum2(part) + bp ;  h2 = LN(x1)*g + b
__global__ __launch_bounds__(256) void redln(
    const unsigned short* __restrict__ part,  // [2][MROWS][CDIM] bf16
    const float* __restrict__ bias, const float* __restrict__ x,
    float* __restrict__ x1, const float* __restrict__ g,
    const float* __restrict__ bb, unsigned short* __restrict__ h2) {
  int row = blockIdx.x;
  int tid = threadIdx.x;
  float v[3];
  float s = 0.f;
#pragma unroll
  for (int i = 0; i < 3; ++i) {
    int c = tid + i * 256;
    size_t idx = (size_t)row * CDIM + c;
    float t = bf2f(part[idx]) + bf2f(part[(size_t)MROWS * CDIM + idx]) + bias[c] + x[idx];
    v[i] = t;
    x1[idx] = t;
    s += t;
  }
#pragma unroll
  for (int m = 1; m < 64; m <<= 1) s += __shfl_xor(s, m);
  __shared__ float red[8];
  int w = tid >> 6;
  if ((tid & 63) == 0) red[w] = s;
  __syncthreads();
  float mean = (red[0] + red[1] + red[2] + red[3]) * (1.f / CDIM);
  float vs = 0.f;
#pragma unroll
  for (int i = 0; i < 3; ++i) { float d = v[i] - mean; vs += d * d; }
#pragma unroll
  for (int m = 1; m < 64; m <<= 1) vs += __shfl_xor(vs, m);
  if ((tid & 63) == 0) red[4 + w] = vs;
  __syncthreads();
  float var = (red[4] + red[5] + red[6] + red[7]) * (1.f / CDIM);
  float rstd = rsqrtf(var + 1e-5f);
  unsigned short* orow = h2 + (size_t)row * CDIM;
#pragma unroll
  for (int i = 0; i < 3; ++i) {
    int c = tid + i * 256;
    orow[c] = f2bf((v[i] - mean) * rstd * g[c] + bb[c]);
  }
}

// ------------- bf16 MFMA GEMM: m97 structure, optional split-K -------------
// 128x128 tile, BK=64, 4 waves each owning 64x64. Single-buffer LDS.
// EPI 0: scatter QKV (Q pre-scaled; V via LDS-bounce transpose -> [bh][D][T])
// EPI 1: outf = acc + bias + aux   EPI 2: outb = relu(acc+bias)
// EPI 3: outf = aux + relu(acc + bias)   EPI 4: bf16 partial [split][M][N]
template <int EPI, int SPLITK = 1>
__global__ __launch_bounds__(256) void gemm_bt(
    const unsigned short* __restrict__ A, const unsigned short* __restrict__ BT,
    int M, int N, int K,
    const float* __restrict__ bias, const float* __restrict__ aux,
    float* __restrict__ outf, unsigned short* __restrict__ outb,
    unsigned short* __restrict__ qo, unsigned short* __restrict__ ko,
    unsigned short* __restrict__ vo) {
  // EPI0 needs a 128x136 transpose buffer aliased over the staging LDS
  constexpr int SH_CNT = (EPI == 0) ? 128 * 136 : 2 * 128 * 64;
  __shared__ unsigned short sh[SH_CNT];
  unsigned short* As = sh;
  unsigned short* Bs = sh + 128 * 64;
  int tid = threadIdx.x;
  int lane = tid & 63, wave = tid >> 6;
  int wr = wave >> 1, wc = wave & 1;
  int l15 = lane & 15, lg = lane >> 4;
  int lr = lane >> 3, lc = lane & 7;
  // bijective XCD-chunked swizzle (gridDim.x divisible by 8)
  int chunk = gridDim.x >> 3;
  int logical = (blockIdx.x & 7) * chunk + (blockIdx.x >> 3);
  int mt = M >> 7;
  int tiles = mt * (N >> 7);
  int split = logical / tiles;
  int tl = logical % tiles;
  size_t bm = (size_t)(tl % mt) * 128, bn = (size_t)(tl / mt) * 128;
  int Ks = K / SPLITK;
  int kbeg = split * Ks, kend = kbeg + Ks;
  f32x4 acc[4][4] = {};

  for (int kt = kbeg; kt < kend; kt += 64) {
#pragma unroll
    for (int i = 0; i < 4; ++i) {
      int r0 = (wave * 4 + i) * 8;
      gload16(A + (bm + r0 + lr) * K + kt + (lc ^ lr) * 8, &As[r0 * 64]);
      gload16(BT + (bn + r0 + lr) * K + kt + (lc ^ lr) * 8, &Bs[r0 * 64]);
    }
    __syncthreads();
    __builtin_amdgcn_s_setprio(1);
#pragma unroll
    for (int kk = 0; kk < 64; kk += 32) {
      int kb = kk + lg * 8;
      short8 af[4], bfr[4];
#pragma unroll
      for (int m = 0; m < 4; ++m) {
        int row = wr * 64 + m * 16 + l15;
        af[m] = *reinterpret_cast<const short8*>(&As[row * 64 + (kb ^ ((row & 7) << 3))]);
      }
#pragma unroll
      for (int n = 0; n < 4; ++n) {
        int row = wc * 64 + n * 16 + l15;
        bfr[n] = *reinterpret_cast<const short8*>(&Bs[row * 64 + (kb ^ ((row & 7) << 3))]);
      }
#pragma unroll
      for (int m = 0; m < 4; ++m)
#pragma unroll
        for (int n = 0; n < 4; ++n)
          acc[m][n] = __builtin_amdgcn_mfma_f32_16x16x32_bf16(af[m], bfr[n], acc[m][n], 0, 0, 0);
    }
    __builtin_amdgcn_s_setprio(0);
    __syncthreads();
  }

  if constexpr (EPI == 0) {
    if (bn >= 1536) {
      // ---- V block: LDS-bounce transpose, then coalesced [bh][D][T] writes ----
#pragma unroll
      for (int m = 0; m < 4; ++m)
#pragma unroll
        for (int n = 0; n < 4; ++n)
#pragma unroll
          for (int r = 0; r < 4; ++r) {
            int rowL = wr * 64 + m * 16 + lg * 4 + r;
            int c = wc * 64 + n * 16 + l15;
            sh[c * 136 + rowL] = f2bf(acc[m][n][r]);
          }
      __syncthreads();
      int bb = (int)(bm >> 11);
      int t0g = (int)(bm & 2047);
      int vbase = (int)bn - 1536;
      // 128 cols x 16 int4-chunks = 2048 chunks; 256 threads x 8 iters
#pragma unroll
      for (int it = 0; it < 8; ++it) {
        int ch = it * 256 + tid;
        int c = ch >> 4, tlc = (ch & 15) * 8;
        int vcol = vbase + c;
        int hh = vcol >> 6, dd = vcol & 63;
        *reinterpret_cast<int4*>(
            vo + (((size_t)(bb * NHEAD + hh)) * DHEAD + dd) * TSEQ + t0g + tlc) =
            *reinterpret_cast<const int4*>(&sh[c * 136 + tlc]);
      }
    } else {
      // ---- Q/K blocks: direct stores ----
#pragma unroll
      for (int m = 0; m < 4; ++m)
#pragma unroll
        for (int n = 0; n < 4; ++n)
#pragma unroll
          for (int r = 0; r < 4; ++r) {
            int row = (int)bm + wr * 64 + m * 16 + lg * 4 + r;
            int col = (int)bn + wc * 64 + n * 16 + l15;
            float val = acc[m][n][r];
            int proj = col / CDIM, rem = col % CDIM;
            int h = rem >> 6, d = rem & 63;
            int b = row >> 11, t = row & (TSEQ - 1);
            if (proj == 0) {
              // Q pre-scaled by 768^-0.5 * log2(e) so attn uses exp2 directly
              qo[(((size_t)(b * NHEAD + h)) * TSEQ + t) * DHEAD + d] =
                  f2bf(val * 0.05205877247186126f);
            } else {
              ko[(((size_t)(b * NHEAD + h)) * TSEQ + t) * DHEAD + d] = f2bf(val);
            }
          }
    }
  } else {
#pragma unroll
    for (int m = 0; m < 4; ++m) {
#pragma unroll
      for (int n = 0; n < 4; ++n) {
#pragma unroll
        for (int r = 0; r < 4; ++r) {
          int row = (int)bm + wr * 64 + m * 16 + lg * 4 + r;
          int col = (int)bn + wc * 64 + n * 16 + l15;
          float val = acc[m][n][r];
          if constexpr (EPI == 1) {
            size_t idx = (size_t)row * CDIM + col;
            outf[idx] = val + bias[col] + aux[idx];
          } else if constexpr (EPI == 2) {
            size_t idx = (size_t)row * FDIM + col;
            outb[idx] = f2bf(fmaxf(val + bias[col], 0.f));
          } else if constexpr (EPI == 3) {
            size_t idx = (size_t)row * CDIM + col;
            outf[idx] = aux[idx] + fmaxf(val + bias[col], 0.f);
          } else {
            // bf16 partial: [split][M][N]
            outb[(size_t)split * M * N + (size_t)row * N + col] = f2bf(val);
          }
        }
      }
    }
  }
}

// ------------- FF2 split-K reduce: out = aux + relu(sum(part) + bias) -------------
template <int NPART, bool RELU>
__global__ __launch_bounds__(256) void reduce_k(
    const unsigned short* __restrict__ part,  // [NPART][MROWS][CDIM] bf16
    const float* __restrict__ bias, const float* __restrict__ aux,
    float* __restrict__ out) {
  int e = (blockIdx.x * 256 + threadIdx.x) * 4;
  int col = e % CDIM;
  float4 xv = *reinterpret_cast<const float4*>(aux + e);
  float4 bv = *reinterpret_cast<const float4*>(bias + col);
  float s0 = 0.f, s1 = 0.f, s2 = 0.f, s3 = 0.f;
#pragma unroll
  for (int p = 0; p < NPART; ++p) {
    short4 pv = *reinterpret_cast<const short4*>(part + (size_t)p * MROWS * CDIM + e);
    s0 += bf2f((unsigned short)pv.x);
    s1 += bf2f((unsigned short)pv.y);
    s2 += bf2f((unsigned short)pv.z);
    s3 += bf2f((unsigned short)pv.w);
  }
  float4 ov;
  if constexpr (RELU) {
    ov.x = xv.x + fmaxf(s0 + bv.x, 0.f);
    ov.y = xv.y + fmaxf(s1 + bv.y, 0.f);
    ov.z = xv.z + fmaxf(s2 + bv.z, 0.f);
    ov.w = xv.w + fmaxf(s3 + bv.w, 0.f);
  } else {
    ov.x = xv.x + s0 + bv.x;
    ov.y = xv.y + s1 + bv.y;
    ov.z = xv.z + s2 + bv.z;
    ov.w = xv.w + s3 + bv.w;
  }
  *reinterpret_cast<float4*>(out + e) = ov;
}

// ------------- causal flash attention v9: cross-iteration QK/PV pipeline ----
// Iter body: { stage(t+1) | PV(t-1) | QK(t) -> SM(t) -> write P(t) }.
// PV(t-1)'s P was written a full iteration ago (LDS turnaround hidden) and
// its V/P reads are independent of iter t -> PV MFMA overlaps SM VALU.
// K 2-buf (ahead-1, drained per iter), V 3-buf (PV reads t-1 while t+1
// streams in; distinct mod 3), P 2-buf per wave. One barrier per iter.
// Balanced stripe pairs (31-p, p): every block exactly 33 tiles.
__global__ __launch_bounds__(256) void attn_kernel(
    const unsigned short* __restrict__ Q, const unsigned short* __restrict__ Kd,
    const unsigned short* __restrict__ VT, unsigned short* __restrict__ O) {
  __shared__ unsigned short Kl[2][64 * 64];
  __shared__ unsigned short Vl[3][64 * 64];
  __shared__ unsigned short plds[4][2][16 * 64];
  int tid = threadIdx.x;
  int wave = tid >> 6, lane = tid & 63;
  int l15 = lane & 15, lg = lane >> 4;
  int bid = blockIdx.x;
  int xcd = bid & 7, idx = bid >> 3;     // 48 blocks per XCD
  int bh = xcd * 3 + idx / 16;           // 3 heads per XCD (L2 locality)
  int p = idx & 15;                      // pair index: stripes (31-p, p)
  const unsigned short* qp = Q + (size_t)bh * TSEQ * DHEAD;
  const unsigned short* kp = Kd + (size_t)bh * TSEQ * DHEAD;
  const unsigned short* vp = VT + (size_t)bh * DHEAD * TSEQ;
  int b = bh / NHEAD, h = bh % NHEAD;

  short8 ones;
  {
    unsigned short ov = (l15 == 0) ? (unsigned short)0x3F80 : (unsigned short)0;
#pragma unroll
    for (int j = 0; j < 8; ++j) ones[j] = (short)ov;
  }

  int lr = lane >> 3, lc = lane & 7;
  int jsw = lc ^ lr;  // pre-swizzled source col-block

  auto stageK = [&](int t, int buf) {
    int s0 = t * 64;
#pragma unroll
    for (int i = 0; i < 2; ++i) {
      int r0 = (wave * 2 + i) * 8;
      gload16(kp + (size_t)(s0 + r0 + lr) * DHEAD + jsw * 8, &Kl[buf][r0 * 64]);
    }
  };
  auto stageV = [&](int t, int buf) {
    int s0 = t * 64;
#pragma unroll
    for (int i = 0; i < 2; ++i) {
      int r0 = (wave * 2 + i) * 8;
      gload16(vp + (size_t)(r0 + lr) * TSEQ + s0 + jsw * 8, &Vl[buf][r0 * 64]);
    }
  };

  auto run_stripe = [&](int stripe) {
    int qbase = stripe * 64 + wave * 16;
    int nt = stripe + 1;  // tiles of 64 k
    short8 qf[2];
#pragma unroll
    for (int kk = 0; kk < 2; ++kk)
      qf[kk] = *reinterpret_cast<const short8*>(
          qp + (size_t)(qbase + l15) * DHEAD + kk * 32 + lg * 8);
    f32x4 oacc[5] = {};  // [0..3] O d-tiles, [4] row-sum column

    // PV of tile tpv: P from plds[wave][tpv&1], V from Vl[tpv%3]
    auto pv = [&](int tpv) {
      const unsigned short* pb = plds[wave][tpv & 1];
      int vb = tpv % 3;
      int prsw = (l15 & 7) << 3;
      short8 pa0 = *reinterpret_cast<const short8*>(&pb[l15 * 64 + ((lg * 8) ^ prsw)]);
      short8 pa1 = *reinterpret_cast<const short8*>(&pb[l15 * 64 + ((32 + lg * 8) ^ prsw)]);
      __builtin_amdgcn_s_setprio(1);
#pragma unroll
      for (int n = 0; n < 4; ++n) {
        int row = n * 16 + l15;
        int sw = row & 7;
        short8 vf0 = *reinterpret_cast<const short8*>(&Vl[vb][row * 64 + ((lg ^ sw) * 8)]);
        oacc[n] = __builtin_amdgcn_mfma_f32_16x16x32_bf16(pa0, vf0, oacc[n], 0, 0, 0);
        short8 vf1 = *reinterpret_cast<const short8*>(&Vl[vb][row * 64 + (((4 + lg) ^ sw) * 8)]);
        oacc[n] = __builtin_amdgcn_mfma_f32_16x16x32_bf16(pa1, vf1, oacc[n], 0, 0, 0);
      }
      oacc[4] = __builtin_amdgcn_mfma_f32_16x16x32_bf16(pa0, ones, oacc[4], 0, 0, 0);
      oacc[4] = __builtin_amdgcn_mfma_f32_16x16x32_bf16(pa1, ones, oacc[4], 0, 0, 0);
      __builtin_amdgcn_s_setprio(0);
    };

    // prologue: stage tile 0 (K and V)
    stageK(0, 0);
    stageV(0, 0);
    asm volatile("s_waitcnt vmcnt(0)" ::: "memory");
    __builtin_amdgcn_s_barrier();

    for (int t = 0; t < nt; ++t) {
      if (t + 1 < nt) {
        stageV(t + 1, (t + 1) % 3);   // consumed in iter t+2 (PV(t+1))
        stageK(t + 1, (t + 1) & 1);   // consumed in iter t+1 (QK(t+1))
      }
      // ---- PV(t-1): fully independent of this iter's QK/SM ----
      if (t > 0) pv(t - 1);
      // ---- QK(t) ----
      f32x4 sacc[4] = {};
      int kb = t & 1;
      __builtin_amdgcn_s_setprio(1);
#pragma unroll
      for (int st = 0; st < 4; ++st) {
        int row = st * 16 + l15;
        int sw = row & 7;
#pragma unroll
        for (int kk = 0; kk < 2; ++kk) {
          short8 kf = *reinterpret_cast<const short8*>(
              &Kl[kb][row * 64 + (((kk * 4 + lg) ^ sw) * 8)]);
          sacc[st] = __builtin_amdgcn_mfma_f32_16x16x32_bf16(qf[kk], kf, sacc[st], 0, 0, 0);
        }
      }
      __builtin_amdgcn_s_setprio(0);
      // ---- SM(t): exact softmax numerator (Q pre-scaled, shift C=0) ----
      unsigned short* pw = plds[wave][t & 1];
      bool last = (t == nt - 1);  // only the last tile crosses the diagonal
      int s0 = t * 64;
#pragma unroll
      for (int r = 0; r < 4; ++r) {
        int qrow = qbase + lg * 4 + r;
        int prow = lg * 4 + r;
        int psw = (prow & 7) << 3;
        if (last) {
#pragma unroll
          for (int st = 0; st < 4; ++st) {
            float pvx = exp2f(sacc[st][r]);
            if (s0 + st * 16 + l15 > qrow) pvx = 0.f;
            pw[prow * 64 + ((st * 16 + l15) ^ psw)] = f2bf(pvx);
          }
        } else {
#pragma unroll
          for (int st = 0; st < 4; ++st)
            pw[prow * 64 + ((st * 16 + l15) ^ psw)] = f2bf(exp2f(sacc[st][r]));
        }
      }
      // staged DMAs had the whole iteration to land; drain + publish
      asm volatile("s_waitcnt vmcnt(0)" ::: "memory");
      __builtin_amdgcn_s_barrier();
    }
    // epilogue: final PV
    pv(nt - 1);

#pragma unroll
    for (int r = 0; r < 4; ++r) {
      float lsum = __shfl(oacc[4][r], lane & 48);  // col 0 of ones-tile
      float inv = 1.f / lsum;
      int row = qbase + lg * 4 + r;
#pragma unroll
      for (int n = 0; n < 4; ++n)
        O[(size_t)(b * TSEQ + row) * CDIM + h * DHEAD + n * 16 + l15] =
            f2bf(oacc[n][r] * inv);
    }
  };

  run_stripe(31 - p);  // heavy stripe
  run_stripe(p);       // light stripe -> every block does exactly 33 tiles
}

extern "C" void kernel_launch(void* const* d_in, const int* in_sizes, int n_in,
                              void* d_out, int out_size, void* d_ws, size_t ws_size,
                              hipStream_t stream) {
  const float* x    = (const float*)d_in[0];
  const float* Wq   = (const float*)d_in[1];
  const float* Wk   = (const float*)d_in[2];
  const float* Wv   = (const float*)d_in[3];
  const float* Wp   = (const float*)d_in[4];
  const float* bp   = (const float*)d_in[5];
  const float* W1   = (const float*)d_in[6];
  const float* b1   = (const float*)d_in[7];
  const float* W2   = (const float*)d_in[8];
  const float* b2   = (const float*)d_in[9];
  const float* ln1g = (const float*)d_in[10];
  const float* ln1b = (const float*)d_in[11];
  const float* ln2g = (const float*)d_in[12];
  const float* ln2b = (const float*)d_in[13];
  float* out = (float*)d_out;

  char* ws = (char*)d_ws;
  auto alloc = [&](size_t bytes) {
    char* p = ws;
    ws += (bytes + 255) & ~(size_t)255;
    return p;
  };
  unsigned short* h1    = (unsigned short*)alloc((size_t)MROWS * CDIM * 2);
  unsigned short* WqkvT = (unsigned short*)alloc((size_t)3 * CDIM * CDIM * 2);
  unsigned short* WpT   = (unsigned short*)alloc((size_t)CDIM * CDIM * 2);
  unsigned short* W1T   = (unsigned short*)alloc((size_t)FDIM * CDIM * 2);
  unsigned short* W2T   = (unsigned short*)alloc((size_t)CDIM * FDIM * 2);
  unsigned short* Qb    = (unsigned short*)alloc((size_t)BH * TSEQ * DHEAD * 2);
  unsigned short* Kb    = (unsigned short*)alloc((size_t)BH * TSEQ * DHEAD * 2);
  unsigned short* VTb   = (unsigned short*)alloc((size_t)BH * TSEQ * DHEAD * 2);
  unsigned short* AO    = (unsigned short*)alloc((size_t)MROWS * CDIM * 2);
  float*          x1    = (float*)alloc((size_t)MROWS * CDIM * 4);
  unsigned short* h2    = (unsigned short*)alloc((size_t)MROWS * CDIM * 2);
  unsigned short* a1    = (unsigned short*)alloc((size_t)MROWS * FDIM * 2);
  // split-K partials reuse the dead [Qb..] region:
  // proj: 2 x 6.29MB = Qb+Kb.  FF2: 4 x 6.29MB = Qb..AO.
  unsigned short* partP = Qb;

  // weight packs + LN1 fused into one launch
  prep_all<<<11008, 256, 0, stream>>>(Wq, Wk, Wv, Wp, W1, W2,
                                      WqkvT, WpT, W1T, W2T, x, ln1g, ln1b, h1);
  // QKV projection (V via LDS-bounce transpose into VTb; Q pre-scaled)
  gemm_bt<0><<<576, 256, 0, stream>>>(h1, WqkvT, MROWS, 3 * CDIM, CDIM,
                                      nullptr, nullptr, nullptr, nullptr, Qb, Kb, VTb);
  // attention
  attn_kernel<<<384, 256, 0, stream>>>(Qb, Kb, VTb, AO);
  // output projection split-K=2: bf16 partials into dead Qb/Kb
  gemm_bt<4, 2><<<384, 256, 0, stream>>>(AO, WpT, MROWS, CDIM, CDIM,
                                         nullptr, nullptr, nullptr, partP,
                                         nullptr, nullptr, nullptr);
  // fused reduce + LN2: x1 = x + sum2 + bp ; h2 = LN(x1)
  redln<<<4096, 256, 0, stream>>>(partP, bp, x, x1, ln2g, ln2b, h2);
  // FF1 (+ReLU) -> a1 bf16
  gemm_bt<2><<<768, 256, 0, stream>>>(h2, W1T, MROWS, FDIM, CDIM,
                                      b1, nullptr, nullptr, a1, nullptr, nullptr, nullptr);
  // FF2 split-K=4: bf16 partials into dead [Qb..AO] region
  gemm_bt<4, 4><<<768, 256, 0, stream>>>(a1, W2T, MROWS, CDIM, FDIM,
                                         nullptr, nullptr, nullptr, partP,
                                         nullptr, nullptr, nullptr);
  // reduce: out = x1 + relu(sum4 + b2)
  reduce_k<4, true><<<3072, 256, 0, stream>>>(partP, b2, x1, out);
}

// Round 17
// 163.657 us; speedup vs baseline: 1.0115x; 1.0115x over previous
//
#include <hip/hip_runtime.h>
#include <hip/hip_bf16.h>

// Problem constants
#define TSEQ 2048
#define CDIM 768
#define NHEAD 12
#define DHEAD 64
#define FDIM 3072
#define MROWS 4096   // B*T
#define BH 24        // B*H

typedef __attribute__((ext_vector_type(8))) short short8;
typedef __attribute__((ext_vector_type(4))) float f32x4;

__device__ inline unsigned short f2bf(float f) {
  __hip_bfloat16 h = __float2bfloat16(f);
  return __builtin_bit_cast(unsigned short, h);
}
__device__ inline float bf2f(unsigned short u) {
  unsigned int v = ((unsigned int)u) << 16;
  return __builtin_bit_cast(float, v);
}

// async global->LDS DMA, 16B per lane; LDS dest = wave-uniform base + lane*16
__device__ inline void gload16(const unsigned short* g, unsigned short* l) {
  __builtin_amdgcn_global_load_lds(
      (const __attribute__((address_space(1))) unsigned int*)g,
      (__attribute__((address_space(3))) unsigned int*)l, 16, 0, 0);
}

// ------------- fused prep: weight packs + LN1 in one launch -------------
__global__ __launch_bounds__(256) void prep_all(
    const float* __restrict__ Wq, const float* __restrict__ Wk,
    const float* __restrict__ Wv, const float* __restrict__ Wp,
    const float* __restrict__ W1, const float* __restrict__ W2,
    unsigned short* __restrict__ WqkvT, unsigned short* __restrict__ WpT,
    unsigned short* __restrict__ W1T, unsigned short* __restrict__ W2T,
    const float* __restrict__ x, const float* __restrict__ ln1g,
    const float* __restrict__ ln1b, unsigned short* __restrict__ h1) {
  __shared__ float tile[32][33];
  __shared__ float red[8];
  int b = blockIdx.x;
  if (b >= 6912) {
    // ---- LayerNorm path ----
    int row = b - 6912;
    int tid = threadIdx.x;
    const float* xr = x + (size_t)row * CDIM;
    float v[3];
    float s = 0.f;
#pragma unroll
    for (int i = 0; i < 3; ++i) { v[i] = xr[tid + i * 256]; s += v[i]; }
#pragma unroll
    for (int m = 1; m < 64; m <<= 1) s += __shfl_xor(s, m);
    int w = tid >> 6;
    if ((tid & 63) == 0) red[w] = s;
    __syncthreads();
    float mean = (red[0] + red[1] + red[2] + red[3]) * (1.f / CDIM);
    float vs = 0.f;
#pragma unroll
    for (int i = 0; i < 3; ++i) { float d = v[i] - mean; vs += d * d; }
#pragma unroll
    for (int m = 1; m < 64; m <<= 1) vs += __shfl_xor(vs, m);
    if ((tid & 63) == 0) red[4 + w] = vs;
    __syncthreads();
    float var = (red[4] + red[5] + red[6] + red[7]) * (1.f / CDIM);
    float rstd = rsqrtf(var + 1e-5f);
    unsigned short* orow = h1 + (size_t)row * CDIM;
#pragma unroll
    for (int i = 0; i < 3; ++i) {
      int c = tid + i * 256;
      orow[c] = f2bf((v[i] - mean) * rstd * ln1g[c] + ln1b[c]);
    }
    return;
  }
  int xx = threadIdx.x & 31, y = threadIdx.x >> 5;
  if (b < 1728) {
    int cx = b % 24, dy = (b / 24) % 2, ph = b / 48;
    int proj = ph / NHEAD, h = ph % NHEAD;
    const float* in = (proj == 0 ? Wq : (proj == 1 ? Wk : Wv)) + (size_t)h * CDIM * DHEAD;
    int c0 = cx * 32, d0 = dy * 32;
#pragma unroll
    for (int i = 0; i < 4; ++i)
      tile[y + i * 8][xx] = in[(size_t)(c0 + y + i * 8) * DHEAD + d0 + xx];
    __syncthreads();
#pragma unroll
    for (int i = 0; i < 4; ++i)
      WqkvT[(size_t)(proj * CDIM + h * DHEAD + d0 + y + i * 8) * CDIM + c0 + xx] =
          f2bf(tile[xx][y + i * 8]);
  } else {
    const float* in;
    unsigned short* out;
    int R, C, bx, by;
    if (b < 2304) {
      int b2 = b - 1728;
      in = Wp; out = WpT; R = CDIM; C = CDIM; bx = b2 % 24; by = b2 / 24;
    } else if (b < 4608) {
      int b2 = b - 2304;
      in = W1; out = W1T; R = CDIM; C = FDIM; bx = b2 % 96; by = b2 / 96;
    } else {
      int b2 = b - 4608;
      in = W2; out = W2T; R = FDIM; C = CDIM; bx = b2 % 24; by = b2 / 24;
    }
    int c0 = bx * 32, r0 = by * 32;
#pragma unroll
    for (int i = 0; i < 4; ++i)
      tile[y + i * 8][xx] = in[(size_t)(r0 + y + i * 8) * C + c0 + xx];
    __syncthreads();
#pragma unroll
    for (int i = 0; i < 4; ++i)
      out[(size_t)(c0 + y + i * 8) * R + r0 + xx] = f2bf(tile[xx][y + i * 8]);
  }
}

// ------------- fused proj split-K reduce + LN2 -------------
// x1 = x + sum2(part) + bp ;  h2 = LN(x1)*g + b
__global__ __launch_bounds__(256) void redln(
    const unsigned short* __restrict__ part,  // [2][MROWS][CDIM] bf16
    const float* __restrict__ bias, const float* __restrict__ x,
    float* __restrict__ x1, const float* __restrict__ g,
    const float* __restrict__ bb, unsigned short* __restrict__ h2) {
  int row = blockIdx.x;
  int tid = threadIdx.x;
  float v[3];
  float s = 0.f;
#pragma unroll
  for (int i = 0; i < 3; ++i) {
    int c = tid + i * 256;
    size_t idx = (size_t)row * CDIM + c;
    float t = bf2f(part[idx]) + bf2f(part[(size_t)MROWS * CDIM + idx]) + bias[c] + x[idx];
    v[i] = t;
    x1[idx] = t;
    s += t;
  }
#pragma unroll
  for (int m = 1; m < 64; m <<= 1) s += __shfl_xor(s, m);
  __shared__ float red[8];
  int w = tid >> 6;
  if ((tid & 63) == 0) red[w] = s;
  __syncthreads();
  float mean = (red[0] + red[1] + red[2] + red[3]) * (1.f / CDIM);
  float vs = 0.f;
#pragma unroll
  for (int i = 0; i < 3; ++i) { float d = v[i] - mean; vs += d * d; }
#pragma unroll
  for (int m = 1; m < 64; m <<= 1) vs += __shfl_xor(vs, m);
  if ((tid & 63) == 0) red[4 + w] = vs;
  __syncthreads();
  float var = (red[4] + red[5] + red[6] + red[7]) * (1.f / CDIM);
  float rstd = rsqrtf(var + 1e-5f);
  unsigned short* orow = h2 + (size_t)row * CDIM;
#pragma unroll
  for (int i = 0; i < 3; ++i) {
    int c = tid + i * 256;
    orow[c] = f2bf((v[i] - mean) * rstd * g[c] + bb[c]);
  }
}

// ------------- bf16 MFMA GEMM: m97 structure, optional split-K -------------
// 128x128 tile, BK=64, 4 waves each owning 64x64. Single-buffer LDS.
// EPI 0: scatter QKV (Q pre-scaled; V via LDS-bounce transpose -> [bh][D][T])
// EPI 1: outf = acc + bias + aux   EPI 2: outb = relu(acc+bias)
// EPI 3: outf = aux + relu(acc + bias)   EPI 4: bf16 partial [split][M][N]
template <int EPI, int SPLITK = 1>
__global__ __launch_bounds__(256) void gemm_bt(
    const unsigned short* __restrict__ A, const unsigned short* __restrict__ BT,
    int M, int N, int K,
    const float* __restrict__ bias, const float* __restrict__ aux,
    float* __restrict__ outf, unsigned short* __restrict__ outb,
    unsigned short* __restrict__ qo, unsigned short* __restrict__ ko,
    unsigned short* __restrict__ vo) {
  // EPI0 needs a 128x136 transpose buffer aliased over the staging LDS
  constexpr int SH_CNT = (EPI == 0) ? 128 * 136 : 2 * 128 * 64;
  __shared__ unsigned short sh[SH_CNT];
  unsigned short* As = sh;
  unsigned short* Bs = sh + 128 * 64;
  int tid = threadIdx.x;
  int lane = tid & 63, wave = tid >> 6;
  int wr = wave >> 1, wc = wave & 1;
  int l15 = lane & 15, lg = lane >> 4;
  int lr = lane >> 3, lc = lane & 7;
  // bijective XCD-chunked swizzle (gridDim.x divisible by 8)
  int chunk = gridDim.x >> 3;
  int logical = (blockIdx.x & 7) * chunk + (blockIdx.x >> 3);
  int mt = M >> 7;
  int tiles = mt * (N >> 7);
  int split = logical / tiles;
  int tl = logical % tiles;
  size_t bm = (size_t)(tl % mt) * 128, bn = (size_t)(tl / mt) * 128;
  int Ks = K / SPLITK;
  int kbeg = split * Ks, kend = kbeg + Ks;
  f32x4 acc[4][4] = {};

  for (int kt = kbeg; kt < kend; kt += 64) {
#pragma unroll
    for (int i = 0; i < 4; ++i) {
      int r0 = (wave * 4 + i) * 8;
      gload16(A + (bm + r0 + lr) * K + kt + (lc ^ lr) * 8, &As[r0 * 64]);
      gload16(BT + (bn + r0 + lr) * K + kt + (lc ^ lr) * 8, &Bs[r0 * 64]);
    }
    __syncthreads();
    __builtin_amdgcn_s_setprio(1);
#pragma unroll
    for (int kk = 0; kk < 64; kk += 32) {
      int kb = kk + lg * 8;
      short8 af[4], bfr[4];
#pragma unroll
      for (int m = 0; m < 4; ++m) {
        int row = wr * 64 + m * 16 + l15;
        af[m] = *reinterpret_cast<const short8*>(&As[row * 64 + (kb ^ ((row & 7) << 3))]);
      }
#pragma unroll
      for (int n = 0; n < 4; ++n) {
        int row = wc * 64 + n * 16 + l15;
        bfr[n] = *reinterpret_cast<const short8*>(&Bs[row * 64 + (kb ^ ((row & 7) << 3))]);
      }
#pragma unroll
      for (int m = 0; m < 4; ++m)
#pragma unroll
        for (int n = 0; n < 4; ++n)
          acc[m][n] = __builtin_amdgcn_mfma_f32_16x16x32_bf16(af[m], bfr[n], acc[m][n], 0, 0, 0);
    }
    __builtin_amdgcn_s_setprio(0);
    __syncthreads();
  }

  if constexpr (EPI == 0) {
    if (bn >= 1536) {
      // ---- V block: LDS-bounce transpose, then coalesced [bh][D][T] writes ----
#pragma unroll
      for (int m = 0; m < 4; ++m)
#pragma unroll
        for (int n = 0; n < 4; ++n)
#pragma unroll
          for (int r = 0; r < 4; ++r) {
            int rowL = wr * 64 + m * 16 + lg * 4 + r;
            int c = wc * 64 + n * 16 + l15;
            sh[c * 136 + rowL] = f2bf(acc[m][n][r]);
          }
      __syncthreads();
      int bb = (int)(bm >> 11);
      int t0g = (int)(bm & 2047);
      int vbase = (int)bn - 1536;
      // 128 cols x 16 int4-chunks = 2048 chunks; 256 threads x 8 iters
#pragma unroll
      for (int it = 0; it < 8; ++it) {
        int ch = it * 256 + tid;
        int c = ch >> 4, tlc = (ch & 15) * 8;
        int vcol = vbase + c;
        int hh = vcol >> 6, dd = vcol & 63;
        *reinterpret_cast<int4*>(
            vo + (((size_t)(bb * NHEAD + hh)) * DHEAD + dd) * TSEQ + t0g + tlc) =
            *reinterpret_cast<const int4*>(&sh[c * 136 + tlc]);
      }
    } else {
      // ---- Q/K blocks: direct stores ----
#pragma unroll
      for (int m = 0; m < 4; ++m)
#pragma unroll
        for (int n = 0; n < 4; ++n)
#pragma unroll
          for (int r = 0; r < 4; ++r) {
            int row = (int)bm + wr * 64 + m * 16 + lg * 4 + r;
            int col = (int)bn + wc * 64 + n * 16 + l15;
            float val = acc[m][n][r];
            int proj = col / CDIM, rem = col % CDIM;
            int h = rem >> 6, d = rem & 63;
            int b = row >> 11, t = row & (TSEQ - 1);
            if (proj == 0) {
              // Q pre-scaled by 768^-0.5 * log2(e) so attn uses exp2 directly
              qo[(((size_t)(b * NHEAD + h)) * TSEQ + t) * DHEAD + d] =
                  f2bf(val * 0.05205877247186126f);
            } else {
              ko[(((size_t)(b * NHEAD + h)) * TSEQ + t) * DHEAD + d] = f2bf(val);
            }
          }
    }
  } else {
#pragma unroll
    for (int m = 0; m < 4; ++m) {
#pragma unroll
      for (int n = 0; n < 4; ++n) {
#pragma unroll
        for (int r = 0; r < 4; ++r) {
          int row = (int)bm + wr * 64 + m * 16 + lg * 4 + r;
          int col = (int)bn + wc * 64 + n * 16 + l15;
          float val = acc[m][n][r];
          if constexpr (EPI == 1) {
            size_t idx = (size_t)row * CDIM + col;
            outf[idx] = val + bias[col] + aux[idx];
          } else if constexpr (EPI == 2) {
            size_t idx = (size_t)row * FDIM + col;
            outb[idx] = f2bf(fmaxf(val + bias[col], 0.f));
          } else if constexpr (EPI == 3) {
            size_t idx = (size_t)row * CDIM + col;
            outf[idx] = aux[idx] + fmaxf(val + bias[col], 0.f);
          } else {
            // bf16 partial: [split][M][N]
            outb[(size_t)split * M * N + (size_t)row * N + col] = f2bf(val);
          }
        }
      }
    }
  }
}

// ------------- FF2 split-K reduce: out = aux + relu(sum(part) + bias) -------------
template <int NPART, bool RELU>
__global__ __launch_bounds__(256) void reduce_k(
    const unsigned short* __restrict__ part,  // [NPART][MROWS][CDIM] bf16
    const float* __restrict__ bias, const float* __restrict__ aux,
    float* __restrict__ out) {
  int e = (blockIdx.x * 256 + threadIdx.x) * 4;
  int col = e % CDIM;
  float4 xv = *reinterpret_cast<const float4*>(aux + e);
  float4 bv = *reinterpret_cast<const float4*>(bias + col);
  float s0 = 0.f, s1 = 0.f, s2 = 0.f, s3 = 0.f;
#pragma unroll
  for (int p = 0; p < NPART; ++p) {
    short4 pv = *reinterpret_cast<const short4*>(part + (size_t)p * MROWS * CDIM + e);
    s0 += bf2f((unsigned short)pv.x);
    s1 += bf2f((unsigned short)pv.y);
    s2 += bf2f((unsigned short)pv.z);
    s3 += bf2f((unsigned short)pv.w);
  }
  float4 ov;
  if constexpr (RELU) {
    ov.x = xv.x + fmaxf(s0 + bv.x, 0.f);
    ov.y = xv.y + fmaxf(s1 + bv.y, 0.f);
    ov.z = xv.z + fmaxf(s2 + bv.z, 0.f);
    ov.w = xv.w + fmaxf(s3 + bv.w, 0.f);
  } else {
    ov.x = xv.x + s0 + bv.x;
    ov.y = xv.y + s1 + bv.y;
    ov.z = xv.z + s2 + bv.z;
    ov.w = xv.w + s3 + bv.w;
  }
  *reinterpret_cast<float4*>(out + e) = ov;
}

// ------------- causal flash attention v10: v8 body, 2-wave balanced grid ----
// 2-wave/128-thr blocks; each block = BALANCED pair of 32-row stripes
// (63-s, s) -> exactly 33 KV-tile iters per block; 768 blocks = exactly
// 3 blocks/CU, every CU identical work (198 wave-iters; was 264 on critical
// CUs at 384x4-wave). Iteration body identical to v8: 3-buf K/V stage-ahead-2,
// counted vmcnt(8), setprio, exact softmax C=0 (Q pre-scaled).
__global__ __launch_bounds__(128) void attn_kernel(
    const unsigned short* __restrict__ Q, const unsigned short* __restrict__ Kd,
    const unsigned short* __restrict__ VT, unsigned short* __restrict__ O) {
  __shared__ unsigned short Kl[3][64 * 64];
  __shared__ unsigned short Vl[3][64 * 64];
  __shared__ unsigned short plds[2][16 * 64];
  int tid = threadIdx.x;
  int wave = tid >> 6, lane = tid & 63;
  int l15 = lane & 15, lg = lane >> 4;
  int bid = blockIdx.x;
  int xcd = bid & 7, idx = bid >> 3;     // 96 blocks per XCD
  int bh = xcd * 3 + idx / 32;           // 3 heads per XCD (L2 locality)
  int s = idx & 31;                      // pair index: 32-row stripes (63-s, s)
  const unsigned short* qp = Q + (size_t)bh * TSEQ * DHEAD;
  const unsigned short* kp = Kd + (size_t)bh * TSEQ * DHEAD;
  const unsigned short* vp = VT + (size_t)bh * DHEAD * TSEQ;
  unsigned short* pw = plds[wave];
  int b = bh / NHEAD, h = bh % NHEAD;

  short8 ones;
  {
    unsigned short ov = (l15 == 0) ? (unsigned short)0x3F80 : (unsigned short)0;
#pragma unroll
    for (int j = 0; j < 8; ++j) ones[j] = (short)ov;
  }

  int lr = lane >> 3, lc = lane & 7;
  int jsw = lc ^ lr;  // pre-swizzled source col-block

  // 2 waves split the staging: each wave 4 K-DMAs + 4 V-DMAs (8 per stage)
  auto stage = [&](int t, int buf) {
    int s0 = t * 64;
#pragma unroll
    for (int i = 0; i < 4; ++i) {
      int r0 = (wave * 4 + i) * 8;
      gload16(kp + (size_t)(s0 + r0 + lr) * DHEAD + jsw * 8, &Kl[buf][r0 * 64]);
      gload16(vp + (size_t)(r0 + lr) * TSEQ + s0 + jsw * 8, &Vl[buf][r0 * 64]);
    }
  };

  auto run_stripe = [&](int stripe) {   // stripe in [0,64): 32 q-rows
    int qbase = stripe * 32 + wave * 16;
    int nt = (stripe + 2) >> 1;  // ceil((stripe+1)*32 / 64) tiles of 64 k
    short8 qf[2];
#pragma unroll
    for (int kk = 0; kk < 2; ++kk)
      qf[kk] = *reinterpret_cast<const short8*>(
          qp + (size_t)(qbase + l15) * DHEAD + kk * 32 + lg * 8);
    f32x4 oacc[5] = {};  // [0..3] O d-tiles, [4] row-sum column

    stage(0, 0);
    if (nt > 1) {
      stage(1, 1);
      asm volatile("s_waitcnt vmcnt(8)" ::: "memory");  // tile 0 landed; 1 in flight
    } else {
      asm volatile("s_waitcnt vmcnt(0)" ::: "memory");
    }
    __builtin_amdgcn_s_barrier();

    for (int t = 0; t < nt; ++t) {
      int cur = t % 3;
      bool pre2 = (t + 2 < nt);
      if (pre2) stage(t + 2, (t + 2) % 3);  // DMA gets a full iteration to land
      int s0 = t * 64;
      // ---- QK^T ----
      f32x4 sacc[4] = {};
      __builtin_amdgcn_s_setprio(1);
#pragma unroll
      for (int st = 0; st < 4; ++st) {
        int row = st * 16 + l15;
        int sw = row & 7;
#pragma unroll
        for (int kk = 0; kk < 2; ++kk) {
          short8 kf = *reinterpret_cast<const short8*>(
              &Kl[cur][row * 64 + (((kk * 4 + lg) ^ sw) * 8)]);
          sacc[st] = __builtin_amdgcn_mfma_f32_16x16x32_bf16(qf[kk], kf, sacc[st], 0, 0, 0);
        }
      }
      __builtin_amdgcn_s_setprio(0);
      // ---- exact softmax numerator (Q pre-scaled; constant shift C=0) ----
      bool last = (t == nt - 1);  // only the last tile crosses the diagonal
#pragma unroll
      for (int r = 0; r < 4; ++r) {
        int qrow = qbase + lg * 4 + r;
        int prow = lg * 4 + r;
        int psw = (prow & 7) << 3;
        if (last) {
#pragma unroll
          for (int st = 0; st < 4; ++st) {
            float pv = exp2f(sacc[st][r]);
            if (s0 + st * 16 + l15 > qrow) pv = 0.f;
            pw[prow * 64 + ((st * 16 + l15) ^ psw)] = f2bf(pv);
          }
        } else {
#pragma unroll
          for (int st = 0; st < 4; ++st)
            pw[prow * 64 + ((st * 16 + l15) ^ psw)] = f2bf(exp2f(sacc[st][r]));
        }
      }
      int prsw = (l15 & 7) << 3;
      short8 pa0 = *reinterpret_cast<const short8*>(&pw[l15 * 64 + ((lg * 8) ^ prsw)]);
      short8 pa1 = *reinterpret_cast<const short8*>(&pw[l15 * 64 + ((32 + lg * 8) ^ prsw)]);
      // ---- PV + row-sum ----
      __builtin_amdgcn_s_setprio(1);
#pragma unroll
      for (int n = 0; n < 4; ++n) {
        int row = n * 16 + l15;
        int sw = row & 7;
        short8 vf0 = *reinterpret_cast<const short8*>(&Vl[cur][row * 64 + ((lg ^ sw) * 8)]);
        oacc[n] = __builtin_amdgcn_mfma_f32_16x16x32_bf16(pa0, vf0, oacc[n], 0, 0, 0);
        short8 vf1 = *reinterpret_cast<const short8*>(&Vl[cur][row * 64 + (((4 + lg) ^ sw) * 8)]);
        oacc[n] = __builtin_amdgcn_mfma_f32_16x16x32_bf16(pa1, vf1, oacc[n], 0, 0, 0);
      }
      oacc[4] = __builtin_amdgcn_mfma_f32_16x16x32_bf16(pa0, ones, oacc[4], 0, 0, 0);
      oacc[4] = __builtin_amdgcn_mfma_f32_16x16x32_bf16(pa1, ones, oacc[4], 0, 0, 0);
      __builtin_amdgcn_s_setprio(0);
      // tile t+1 must be landed before next iter; keep t+2 in flight
      if (pre2) asm volatile("s_waitcnt vmcnt(8)" ::: "memory");
      else      asm volatile("s_waitcnt vmcnt(0)" ::: "memory");
      __builtin_amdgcn_s_barrier();
    }

#pragma unroll
    for (int r = 0; r < 4; ++r) {
      float lsum = __shfl(oacc[4][r], lane & 48);  // col 0 of ones-tile
      float inv = 1.f / lsum;
      int row = qbase + lg * 4 + r;
#pragma unroll
      for (int n = 0; n < 4; ++n)
        O[(size_t)(b * TSEQ + row) * CDIM + h * DHEAD + n * 16 + l15] =
            f2bf(oacc[n][r] * inv);
    }
  };

  run_stripe(63 - s);  // heavy stripe (32 rows)
  run_stripe(s);       // light stripe -> every block exactly 33 tiles
}

extern "C" void kernel_launch(void* const* d_in, const int* in_sizes, int n_in,
                              void* d_out, int out_size, void* d_ws, size_t ws_size,
                              hipStream_t stream) {
  const float* x    = (const float*)d_in[0];
  const float* Wq   = (const float*)d_in[1];
  const float* Wk   = (const float*)d_in[2];
  const float* Wv   = (const float*)d_in[3];
  const float* Wp   = (const float*)d_in[4];
  const float* bp   = (const float*)d_in[5];
  const float* W1   = (const float*)d_in[6];
  const float* b1   = (const float*)d_in[7];
  const float* W2   = (const float*)d_in[8];
  const float* b2   = (const float*)d_in[9];
  const float* ln1g = (const float*)d_in[10];
  const float* ln1b = (const float*)d_in[11];
  const float* ln2g = (const float*)d_in[12];
  const float* ln2b = (const float*)d_in[13];
  float* out = (float*)d_out;

  char* ws = (char*)d_ws;
  auto alloc = [&](size_t bytes) {
    char* p = ws;
    ws += (bytes + 255) & ~(size_t)255;
    return p;
  };
  unsigned short* h1    = (unsigned short*)alloc((size_t)MROWS * CDIM * 2);
  unsigned short* WqkvT = (unsigned short*)alloc((size_t)3 * CDIM * CDIM * 2);
  unsigned short* WpT   = (unsigned short*)alloc((size_t)CDIM * CDIM * 2);
  unsigned short* W1T   = (unsigned short*)alloc((size_t)FDIM * CDIM * 2);
  unsigned short* W2T   = (unsigned short*)alloc((size_t)CDIM * FDIM * 2);
  unsigned short* Qb    = (unsigned short*)alloc((size_t)BH * TSEQ * DHEAD * 2);
  unsigned short* Kb    = (unsigned short*)alloc((size_t)BH * TSEQ * DHEAD * 2);
  unsigned short* VTb   = (unsigned short*)alloc((size_t)BH * TSEQ * DHEAD * 2);
  unsigned short* AO    = (unsigned short*)alloc((size_t)MROWS * CDIM * 2);
  float*          x1    = (float*)alloc((size_t)MROWS * CDIM * 4);
  unsigned short* h2    = (unsigned short*)alloc((size_t)MROWS * CDIM * 2);
  unsigned short* a1    = (unsigned short*)alloc((size_t)MROWS * FDIM * 2);
  // split-K partials reuse the dead [Qb..] region:
  // proj: 2 x 6.29MB = Qb+Kb.  FF2: 4 x 6.29MB = Qb..AO.
  unsigned short* partP = Qb;

  // weight packs + LN1 fused into one launch
  prep_all<<<11008, 256, 0, stream>>>(Wq, Wk, Wv, Wp, W1, W2,
                                      WqkvT, WpT, W1T, W2T, x, ln1g, ln1b, h1);
  // QKV projection (V via LDS-bounce transpose into VTb; Q pre-scaled)
  gemm_bt<0><<<576, 256, 0, stream>>>(h1, WqkvT, MROWS, 3 * CDIM, CDIM,
                                      nullptr, nullptr, nullptr, nullptr, Qb, Kb, VTb);
  // attention (2-wave balanced grid: 768 blocks, 3/CU exactly)
  attn_kernel<<<768, 128, 0, stream>>>(Qb, Kb, VTb, AO);
  // output projection split-K=2: bf16 partials into dead Qb/Kb
  gemm_bt<4, 2><<<384, 256, 0, stream>>>(AO, WpT, MROWS, CDIM, CDIM,
                                         nullptr, nullptr, nullptr, partP,
                                         nullptr, nullptr, nullptr);
  // fused reduce + LN2: x1 = x + sum2 + bp ; h2 = LN(x1)
  redln<<<4096, 256, 0, stream>>>(partP, bp, x, x1, ln2g, ln2b, h2);
  // FF1 (+ReLU) -> a1 bf16
  gemm_bt<2><<<768, 256, 0, stream>>>(h2, W1T, MROWS, FDIM, CDIM,
                                      b1, nullptr, nullptr, a1, nullptr, nullptr, nullptr);
  // FF2 split-K=4: bf16 partials into dead [Qb..AO] region
  gemm_bt<4, 4><<<768, 256, 0, stream>>>(a1, W2T, MROWS, CDIM, FDIM,
                                         nullptr, nullptr, nullptr, partP,
                                         nullptr, nullptr, nullptr);
  // reduce: out = x1 + relu(sum4 + b2)
  reduce_k<4, true><<<3072, 256, 0, stream>>>(partP, b2, x1, out);
}

// Round 18
// 158.936 us; speedup vs baseline: 1.0416x; 1.0297x over previous
//
#include <hip/hip_runtime.h>
#include <hip/hip_bf16.h>

// Problem constants
#define TSEQ 2048
#define CDIM 768
#define NHEAD 12
#define DHEAD 64
#define FDIM 3072
#define MROWS 4096   // B*T
#define BH 24        // B*H

typedef __attribute__((ext_vector_type(8))) short short8;
typedef __attribute__((ext_vector_type(4))) float f32x4;

__device__ inline unsigned short f2bf(float f) {
  __hip_bfloat16 h = __float2bfloat16(f);
  return __builtin_bit_cast(unsigned short, h);
}
__device__ inline float bf2f(unsigned short u) {
  unsigned int v = ((unsigned int)u) << 16;
  return __builtin_bit_cast(float, v);
}

// async global->LDS DMA, 16B per lane; LDS dest = wave-uniform base + lane*16
__device__ inline void gload16(const unsigned short* g, unsigned short* l) {
  __builtin_amdgcn_global_load_lds(
      (const __attribute__((address_space(1))) unsigned int*)g,
      (__attribute__((address_space(3))) unsigned int*)l, 16, 0, 0);
}

// ------------- fused prep: weight packs + LN1 in one launch -------------
__global__ __launch_bounds__(256) void prep_all(
    const float* __restrict__ Wq, const float* __restrict__ Wk,
    const float* __restrict__ Wv, const float* __restrict__ Wp,
    const float* __restrict__ W1, const float* __restrict__ W2,
    unsigned short* __restrict__ WqkvT, unsigned short* __restrict__ WpT,
    unsigned short* __restrict__ W1T, unsigned short* __restrict__ W2T,
    const float* __restrict__ x, const float* __restrict__ ln1g,
    const float* __restrict__ ln1b, unsigned short* __restrict__ h1) {
  __shared__ float tile[32][33];
  __shared__ float red[8];
  int b = blockIdx.x;
  if (b >= 6912) {
    // ---- LayerNorm path ----
    int row = b - 6912;
    int tid = threadIdx.x;
    const float* xr = x + (size_t)row * CDIM;
    float v[3];
    float s = 0.f;
#pragma unroll
    for (int i = 0; i < 3; ++i) { v[i] = xr[tid + i * 256]; s += v[i]; }
#pragma unroll
    for (int m = 1; m < 64; m <<= 1) s += __shfl_xor(s, m);
    int w = tid >> 6;
    if ((tid & 63) == 0) red[w] = s;
    __syncthreads();
    float mean = (red[0] + red[1] + red[2] + red[3]) * (1.f / CDIM);
    float vs = 0.f;
#pragma unroll
    for (int i = 0; i < 3; ++i) { float d = v[i] - mean; vs += d * d; }
#pragma unroll
    for (int m = 1; m < 64; m <<= 1) vs += __shfl_xor(vs, m);
    if ((tid & 63) == 0) red[4 + w] = vs;
    __syncthreads();
    float var = (red[4] + red[5] + red[6] + red[7]) * (1.f / CDIM);
    float rstd = rsqrtf(var + 1e-5f);
    unsigned short* orow = h1 + (size_t)row * CDIM;
#pragma unroll
    for (int i = 0; i < 3; ++i) {
      int c = tid + i * 256;
      orow[c] = f2bf((v[i] - mean) * rstd * ln1g[c] + ln1b[c]);
    }
    return;
  }
  int xx = threadIdx.x & 31, y = threadIdx.x >> 5;
  if (b < 1728) {
    int cx = b % 24, dy = (b / 24) % 2, ph = b / 48;
    int proj = ph / NHEAD, h = ph % NHEAD;
    const float* in = (proj == 0 ? Wq : (proj == 1 ? Wk : Wv)) + (size_t)h * CDIM * DHEAD;
    int c0 = cx * 32, d0 = dy * 32;
#pragma unroll
    for (int i = 0; i < 4; ++i)
      tile[y + i * 8][xx] = in[(size_t)(c0 + y + i * 8) * DHEAD + d0 + xx];
    __syncthreads();
#pragma unroll
    for (int i = 0; i < 4; ++i)
      WqkvT[(size_t)(proj * CDIM + h * DHEAD + d0 + y + i * 8) * CDIM + c0 + xx] =
          f2bf(tile[xx][y + i * 8]);
  } else {
    const float* in;
    unsigned short* out;
    int R, C, bx, by;
    if (b < 2304) {
      int b2 = b - 1728;
      in = Wp; out = WpT; R = CDIM; C = CDIM; bx = b2 % 24; by = b2 / 24;
    } else if (b < 4608) {
      int b2 = b - 2304;
      in = W1; out = W1T; R = CDIM; C = FDIM; bx = b2 % 96; by = b2 / 96;
    } else {
      int b2 = b - 4608;
      in = W2; out = W2T; R = FDIM; C = CDIM; bx = b2 % 24; by = b2 / 24;
    }
    int c0 = bx * 32, r0 = by * 32;
#pragma unroll
    for (int i = 0; i < 4; ++i)
      tile[y + i * 8][xx] = in[(size_t)(r0 + y + i * 8) * C + c0 + xx];
    __syncthreads();
#pragma unroll
    for (int i = 0; i < 4; ++i)
      out[(size_t)(c0 + y + i * 8) * R + r0 + xx] = f2bf(tile[xx][y + i * 8]);
  }
}

// ------------- fused proj split-K reduce + LN2 -------------
// x1 = x + sum2(part) + bp ;  h2 = LN(x1)*g + b
__global__ __launch_bounds__(256) void redln(
    const unsigned short* __restrict__ part,  // [2][MROWS][CDIM] bf16
    const float* __restrict__ bias, const float* __restrict__ x,
    float* __restrict__ x1, const float* __restrict__ g,
    const float* __restrict__ bb, unsigned short* __restrict__ h2) {
  int row = blockIdx.x;
  int tid = threadIdx.x;
  float v[3];
  float s = 0.f;
#pragma unroll
  for (int i = 0; i < 3; ++i) {
    int c = tid + i * 256;
    size_t idx = (size_t)row * CDIM + c;
    float t = bf2f(part[idx]) + bf2f(part[(size_t)MROWS * CDIM + idx]) + bias[c] + x[idx];
    v[i] = t;
    x1[idx] = t;
    s += t;
  }
#pragma unroll
  for (int m = 1; m < 64; m <<= 1) s += __shfl_xor(s, m);
  __shared__ float red[8];
  int w = tid >> 6;
  if ((tid & 63) == 0) red[w] = s;
  __syncthreads();
  float mean = (red[0] + red[1] + red[2] + red[3]) * (1.f / CDIM);
  float vs = 0.f;
#pragma unroll
  for (int i = 0; i < 3; ++i) { float d = v[i] - mean; vs += d * d; }
#pragma unroll
  for (int m = 1; m < 64; m <<= 1) vs += __shfl_xor(vs, m);
  if ((tid & 63) == 0) red[4 + w] = vs;
  __syncthreads();
  float var = (red[4] + red[5] + red[6] + red[7]) * (1.f / CDIM);
  float rstd = rsqrtf(var + 1e-5f);
  unsigned short* orow = h2 + (size_t)row * CDIM;
#pragma unroll
  for (int i = 0; i < 3; ++i) {
    int c = tid + i * 256;
    orow[c] = f2bf((v[i] - mean) * rstd * g[c] + bb[c]);
  }
}

// ------------- bf16 MFMA GEMM: m97 structure, optional split-K -------------
// 128x128 tile, BK=64, 4 waves each owning 64x64. Single-buffer LDS.
// EPI 0: scatter QKV (Q pre-scaled; V via LDS-bounce transpose -> [bh][D][T])
// EPI 1: outf = acc + bias + aux   EPI 2: outb = relu(acc+bias)
// EPI 3: outf = aux + relu(acc + bias)   EPI 4: bf16 partial [split][M][N]
template <int EPI, int SPLITK = 1>
__global__ __launch_bounds__(256) void gemm_bt(
    const unsigned short* __restrict__ A, const unsigned short* __restrict__ BT,
    int M, int N, int K,
    const float* __restrict__ bias, const float* __restrict__ aux,
    float* __restrict__ outf, unsigned short* __restrict__ outb,
    unsigned short* __restrict__ qo, unsigned short* __restrict__ ko,
    unsigned short* __restrict__ vo) {
  // EPI0 needs a 128x136 transpose buffer aliased over the staging LDS
  constexpr int SH_CNT = (EPI == 0) ? 128 * 136 : 2 * 128 * 64;
  __shared__ unsigned short sh[SH_CNT];
  unsigned short* As = sh;
  unsigned short* Bs = sh + 128 * 64;
  int tid = threadIdx.x;
  int lane = tid & 63, wave = tid >> 6;
  int wr = wave >> 1, wc = wave & 1;
  int l15 = lane & 15, lg = lane >> 4;
  int lr = lane >> 3, lc = lane & 7;
  // bijective XCD-chunked swizzle (gridDim.x divisible by 8)
  int chunk = gridDim.x >> 3;
  int logical = (blockIdx.x & 7) * chunk + (blockIdx.x >> 3);
  int mt = M >> 7;
  int tiles = mt * (N >> 7);
  int split = logical / tiles;
  int tl = logical % tiles;
  size_t bm = (size_t)(tl % mt) * 128, bn = (size_t)(tl / mt) * 128;
  int Ks = K / SPLITK;
  int kbeg = split * Ks, kend = kbeg + Ks;
  f32x4 acc[4][4] = {};

  for (int kt = kbeg; kt < kend; kt += 64) {
#pragma unroll
    for (int i = 0; i < 4; ++i) {
      int r0 = (wave * 4 + i) * 8;
      gload16(A + (bm + r0 + lr) * K + kt + (lc ^ lr) * 8, &As[r0 * 64]);
      gload16(BT + (bn + r0 + lr) * K + kt + (lc ^ lr) * 8, &Bs[r0 * 64]);
    }
    __syncthreads();
    __builtin_amdgcn_s_setprio(1);
#pragma unroll
    for (int kk = 0; kk < 64; kk += 32) {
      int kb = kk + lg * 8;
      short8 af[4], bfr[4];
#pragma unroll
      for (int m = 0; m < 4; ++m) {
        int row = wr * 64 + m * 16 + l15;
        af[m] = *reinterpret_cast<const short8*>(&As[row * 64 + (kb ^ ((row & 7) << 3))]);
      }
#pragma unroll
      for (int n = 0; n < 4; ++n) {
        int row = wc * 64 + n * 16 + l15;
        bfr[n] = *reinterpret_cast<const short8*>(&Bs[row * 64 + (kb ^ ((row & 7) << 3))]);
      }
#pragma unroll
      for (int m = 0; m < 4; ++m)
#pragma unroll
        for (int n = 0; n < 4; ++n)
          acc[m][n] = __builtin_amdgcn_mfma_f32_16x16x32_bf16(af[m], bfr[n], acc[m][n], 0, 0, 0);
    }
    __builtin_amdgcn_s_setprio(0);
    __syncthreads();
  }

  if constexpr (EPI == 0) {
    if (bn >= 1536) {
      // ---- V block: LDS-bounce transpose, then coalesced [bh][D][T] writes ----
#pragma unroll
      for (int m = 0; m < 4; ++m)
#pragma unroll
        for (int n = 0; n < 4; ++n)
#pragma unroll
          for (int r = 0; r < 4; ++r) {
            int rowL = wr * 64 + m * 16 + lg * 4 + r;
            int c = wc * 64 + n * 16 + l15;
            sh[c * 136 + rowL] = f2bf(acc[m][n][r]);
          }
      __syncthreads();
      int bb = (int)(bm >> 11);
      int t0g = (int)(bm & 2047);
      int vbase = (int)bn - 1536;
      // 128 cols x 16 int4-chunks = 2048 chunks; 256 threads x 8 iters
#pragma unroll
      for (int it = 0; it < 8; ++it) {
        int ch = it * 256 + tid;
        int c = ch >> 4, tlc = (ch & 15) * 8;
        int vcol = vbase + c;
        int hh = vcol >> 6, dd = vcol & 63;
        *reinterpret_cast<int4*>(
            vo + (((size_t)(bb * NHEAD + hh)) * DHEAD + dd) * TSEQ + t0g + tlc) =
            *reinterpret_cast<const int4*>(&sh[c * 136 + tlc]);
      }
    } else {
      // ---- Q/K blocks: direct stores ----
#pragma unroll
      for (int m = 0; m < 4; ++m)
#pragma unroll
        for (int n = 0; n < 4; ++n)
#pragma unroll
          for (int r = 0; r < 4; ++r) {
            int row = (int)bm + wr * 64 + m * 16 + lg * 4 + r;
            int col = (int)bn + wc * 64 + n * 16 + l15;
            float val = acc[m][n][r];
            int proj = col / CDIM, rem = col % CDIM;
            int h = rem >> 6, d = rem & 63;
            int b = row >> 11, t = row & (TSEQ - 1);
            if (proj == 0) {
              // Q pre-scaled by 768^-0.5 * log2(e) so attn uses exp2 directly
              qo[(((size_t)(b * NHEAD + h)) * TSEQ + t) * DHEAD + d] =
                  f2bf(val * 0.05205877247186126f);
            } else {
              ko[(((size_t)(b * NHEAD + h)) * TSEQ + t) * DHEAD + d] = f2bf(val);
            }
          }
    }
  } else {
#pragma unroll
    for (int m = 0; m < 4; ++m) {
#pragma unroll
      for (int n = 0; n < 4; ++n) {
#pragma unroll
        for (int r = 0; r < 4; ++r) {
          int row = (int)bm + wr * 64 + m * 16 + lg * 4 + r;
          int col = (int)bn + wc * 64 + n * 16 + l15;
          float val = acc[m][n][r];
          if constexpr (EPI == 1) {
            size_t idx = (size_t)row * CDIM + col;
            outf[idx] = val + bias[col] + aux[idx];
          } else if constexpr (EPI == 2) {
            size_t idx = (size_t)row * FDIM + col;
            outb[idx] = f2bf(fmaxf(val + bias[col], 0.f));
          } else if constexpr (EPI == 3) {
            size_t idx = (size_t)row * CDIM + col;
            outf[idx] = aux[idx] + fmaxf(val + bias[col], 0.f);
          } else {
            // bf16 partial: [split][M][N]
            outb[(size_t)split * M * N + (size_t)row * N + col] = f2bf(val);
          }
        }
      }
    }
  }
}

// ------------- FF2 split-K reduce: out = aux + relu(sum(part) + bias) -------------
template <int NPART, bool RELU>
__global__ __launch_bounds__(256) void reduce_k(
    const unsigned short* __restrict__ part,  // [NPART][MROWS][CDIM] bf16
    const float* __restrict__ bias, const float* __restrict__ aux,
    float* __restrict__ out) {
  int e = (blockIdx.x * 256 + threadIdx.x) * 4;
  int col = e % CDIM;
  float4 xv = *reinterpret_cast<const float4*>(aux + e);
  float4 bv = *reinterpret_cast<const float4*>(bias + col);
  float s0 = 0.f, s1 = 0.f, s2 = 0.f, s3 = 0.f;
#pragma unroll
  for (int p = 0; p < NPART; ++p) {
    short4 pv = *reinterpret_cast<const short4*>(part + (size_t)p * MROWS * CDIM + e);
    s0 += bf2f((unsigned short)pv.x);
    s1 += bf2f((unsigned short)pv.y);
    s2 += bf2f((unsigned short)pv.z);
    s3 += bf2f((unsigned short)pv.w);
  }
  float4 ov;
  if constexpr (RELU) {
    ov.x = xv.x + fmaxf(s0 + bv.x, 0.f);
    ov.y = xv.y + fmaxf(s1 + bv.y, 0.f);
    ov.z = xv.z + fmaxf(s2 + bv.z, 0.f);
    ov.w = xv.w + fmaxf(s3 + bv.w, 0.f);
  } else {
    ov.x = xv.x + s0 + bv.x;
    ov.y = xv.y + s1 + bv.y;
    ov.z = xv.z + s2 + bv.z;
    ov.w = xv.w + s3 + bv.w;
  }
  *reinterpret_cast<float4*>(out + e) = ov;
}

// ------------- causal flash attention v11: occupancy-first ----
// 2-wave/128-thr blocks; each block = ONE 32-row stripe (wave owns 16 rows);
// 1536 blocks = 24 heads x 64 stripes, heavy-first within each XCD -> LPT
// backfill balancing (only ~4 blocks/CU resident, light blocks fill gaps).
// LDS cut to 36 KB (2-buf K/V stage-ahead-1 + per-wave P) -> 4 blocks/CU =
// 2 waves/SIMD (was 1.5). Body identical to v8/v10: exact softmax C=0,
// ones-column row-sum, setprio, pre-swizzled DMA staging.
__global__ __launch_bounds__(128) void attn_kernel(
    const unsigned short* __restrict__ Q, const unsigned short* __restrict__ Kd,
    const unsigned short* __restrict__ VT, unsigned short* __restrict__ O) {
  __shared__ unsigned short Kl[2][64 * 64];
  __shared__ unsigned short Vl[2][64 * 64];
  __shared__ unsigned short plds[2][16 * 64];
  int tid = threadIdx.x;
  int wave = tid >> 6, lane = tid & 63;
  int l15 = lane & 15, lg = lane >> 4;
  int bid = blockIdx.x;
  int xcd = bid & 7, idx = bid >> 3;     // 192 blocks per XCD
  int bh = xcd * 3 + idx % 3;            // 3 heads per XCD (L2 locality)
  int stripe = 63 - idx / 3;             // heavy-first (LPT backfill)
  const unsigned short* qp = Q + (size_t)bh * TSEQ * DHEAD;
  const unsigned short* kp = Kd + (size_t)bh * TSEQ * DHEAD;
  const unsigned short* vp = VT + (size_t)bh * DHEAD * TSEQ;
  unsigned short* pw = plds[wave];
  int b = bh / NHEAD, h = bh % NHEAD;

  short8 ones;
  {
    unsigned short ov = (l15 == 0) ? (unsigned short)0x3F80 : (unsigned short)0;
#pragma unroll
    for (int j = 0; j < 8; ++j) ones[j] = (short)ov;
  }

  int lr = lane >> 3, lc = lane & 7;
  int jsw = lc ^ lr;  // pre-swizzled source col-block

  // 2 waves split the staging: each wave 4 K-DMAs + 4 V-DMAs (8 per stage)
  auto stage = [&](int t, int buf) {
    int s0 = t * 64;
#pragma unroll
    for (int i = 0; i < 4; ++i) {
      int r0 = (wave * 4 + i) * 8;
      gload16(kp + (size_t)(s0 + r0 + lr) * DHEAD + jsw * 8, &Kl[buf][r0 * 64]);
      gload16(vp + (size_t)(r0 + lr) * TSEQ + s0 + jsw * 8, &Vl[buf][r0 * 64]);
    }
  };

  int qbase = stripe * 32 + wave * 16;
  int nt = (stripe >> 1) + 1;  // 64-k tiles covering rows [0, stripe*32+32)
  short8 qf[2];
#pragma unroll
  for (int kk = 0; kk < 2; ++kk)
    qf[kk] = *reinterpret_cast<const short8*>(
        qp + (size_t)(qbase + l15) * DHEAD + kk * 32 + lg * 8);
  f32x4 oacc[5] = {};  // [0..3] O d-tiles, [4] row-sum column

  stage(0, 0);
  asm volatile("s_waitcnt vmcnt(0)" ::: "memory");
  __builtin_amdgcn_s_barrier();

  for (int t = 0; t < nt; ++t) {
    int cur = t & 1;
    if (t + 1 < nt) stage(t + 1, cur ^ 1);  // DMA gets the full compute phase
    int s0 = t * 64;
    // ---- QK^T ----
    f32x4 sacc[4] = {};
    __builtin_amdgcn_s_setprio(1);
#pragma unroll
    for (int st = 0; st < 4; ++st) {
      int row = st * 16 + l15;
      int sw = row & 7;
#pragma unroll
      for (int kk = 0; kk < 2; ++kk) {
        short8 kf = *reinterpret_cast<const short8*>(
            &Kl[cur][row * 64 + (((kk * 4 + lg) ^ sw) * 8)]);
        sacc[st] = __builtin_amdgcn_mfma_f32_16x16x32_bf16(qf[kk], kf, sacc[st], 0, 0, 0);
      }
    }
    __builtin_amdgcn_s_setprio(0);
    // ---- exact softmax numerator (Q pre-scaled; constant shift C=0) ----
    bool last = (t == nt - 1);  // only the last tile crosses the diagonal
#pragma unroll
    for (int r = 0; r < 4; ++r) {
      int qrow = qbase + lg * 4 + r;
      int prow = lg * 4 + r;
      int psw = (prow & 7) << 3;
      if (last) {
#pragma unroll
        for (int st = 0; st < 4; ++st) {
          float pv = exp2f(sacc[st][r]);
          if (s0 + st * 16 + l15 > qrow) pv = 0.f;
          pw[prow * 64 + ((st * 16 + l15) ^ psw)] = f2bf(pv);
        }
      } else {
#pragma unroll
        for (int st = 0; st < 4; ++st)
          pw[prow * 64 + ((st * 16 + l15) ^ psw)] = f2bf(exp2f(sacc[st][r]));
      }
    }
    int prsw = (l15 & 7) << 3;
    short8 pa0 = *reinterpret_cast<const short8*>(&pw[l15 * 64 + ((lg * 8) ^ prsw)]);
    short8 pa1 = *reinterpret_cast<const short8*>(&pw[l15 * 64 + ((32 + lg * 8) ^ prsw)]);
    // ---- PV + row-sum ----
    __builtin_amdgcn_s_setprio(1);
#pragma unroll
    for (int n = 0; n < 4; ++n) {
      int row = n * 16 + l15;
      int sw = row & 7;
      short8 vf0 = *reinterpret_cast<const short8*>(&Vl[cur][row * 64 + ((lg ^ sw) * 8)]);
      oacc[n] = __builtin_amdgcn_mfma_f32_16x16x32_bf16(pa0, vf0, oacc[n], 0, 0, 0);
      short8 vf1 = *reinterpret_cast<const short8*>(&Vl[cur][row * 64 + (((4 + lg) ^ sw) * 8)]);
      oacc[n] = __builtin_amdgcn_mfma_f32_16x16x32_bf16(pa1, vf1, oacc[n], 0, 0, 0);
    }
    oacc[4] = __builtin_amdgcn_mfma_f32_16x16x32_bf16(pa0, ones, oacc[4], 0, 0, 0);
    oacc[4] = __builtin_amdgcn_mfma_f32_16x16x32_bf16(pa1, ones, oacc[4], 0, 0, 0);
    __builtin_amdgcn_s_setprio(0);
    // staged DMAs had the whole compute phase to land; drain + publish
    asm volatile("s_waitcnt vmcnt(0)" ::: "memory");
    __builtin_amdgcn_s_barrier();
  }

#pragma unroll
  for (int r = 0; r < 4; ++r) {
    float lsum = __shfl(oacc[4][r], lane & 48);  // col 0 of ones-tile
    float inv = 1.f / lsum;
    int row = qbase + lg * 4 + r;
#pragma unroll
    for (int n = 0; n < 4; ++n)
      O[(size_t)(b * TSEQ + row) * CDIM + h * DHEAD + n * 16 + l15] =
          f2bf(oacc[n][r] * inv);
  }
}

extern "C" void kernel_launch(void* const* d_in, const int* in_sizes, int n_in,
                              void* d_out, int out_size, void* d_ws, size_t ws_size,
                              hipStream_t stream) {
  const float* x    = (const float*)d_in[0];
  const float* Wq   = (const float*)d_in[1];
  const float* Wk   = (const float*)d_in[2];
  const float* Wv   = (const float*)d_in[3];
  const float* Wp   = (const float*)d_in[4];
  const float* bp   = (const float*)d_in[5];
  const float* W1   = (const float*)d_in[6];
  const float* b1   = (const float*)d_in[7];
  const float* W2   = (const float*)d_in[8];
  const float* b2   = (const float*)d_in[9];
  const float* ln1g = (const float*)d_in[10];
  const float* ln1b = (const float*)d_in[11];
  const float* ln2g = (const float*)d_in[12];
  const float* ln2b = (const float*)d_in[13];
  float* out = (float*)d_out;

  char* ws = (char*)d_ws;
  auto alloc = [&](size_t bytes) {
    char* p = ws;
    ws += (bytes + 255) & ~(size_t)255;
    return p;
  };
  unsigned short* h1    = (unsigned short*)alloc((size_t)MROWS * CDIM * 2);
  unsigned short* WqkvT = (unsigned short*)alloc((size_t)3 * CDIM * CDIM * 2);
  unsigned short* WpT   = (unsigned short*)alloc((size_t)CDIM * CDIM * 2);
  unsigned short* W1T   = (unsigned short*)alloc((size_t)FDIM * CDIM * 2);
  unsigned short* W2T   = (unsigned short*)alloc((size_t)CDIM * FDIM * 2);
  unsigned short* Qb    = (unsigned short*)alloc((size_t)BH * TSEQ * DHEAD * 2);
  unsigned short* Kb    = (unsigned short*)alloc((size_t)BH * TSEQ * DHEAD * 2);
  unsigned short* VTb   = (unsigned short*)alloc((size_t)BH * TSEQ * DHEAD * 2);
  unsigned short* AO    = (unsigned short*)alloc((size_t)MROWS * CDIM * 2);
  float*          x1    = (float*)alloc((size_t)MROWS * CDIM * 4);
  unsigned short* h2    = (unsigned short*)alloc((size_t)MROWS * CDIM * 2);
  unsigned short* a1    = (unsigned short*)alloc((size_t)MROWS * FDIM * 2);
  // split-K partials reuse the dead [Qb..] region:
  // proj: 2 x 6.29MB = Qb+Kb.  FF2: 4 x 6.29MB = Qb..AO.
  unsigned short* partP = Qb;

  // weight packs + LN1 fused into one launch
  prep_all<<<11008, 256, 0, stream>>>(Wq, Wk, Wv, Wp, W1, W2,
                                      WqkvT, WpT, W1T, W2T, x, ln1g, ln1b, h1);
  // QKV projection (V via LDS-bounce transpose into VTb; Q pre-scaled)
  gemm_bt<0><<<576, 256, 0, stream>>>(h1, WqkvT, MROWS, 3 * CDIM, CDIM,
                                      nullptr, nullptr, nullptr, nullptr, Qb, Kb, VTb);
  // attention (occupancy-first: 1536 blocks, 4 resident/CU, LPT backfill)
  attn_kernel<<<1536, 128, 0, stream>>>(Qb, Kb, VTb, AO);
  // output projection split-K=2: bf16 partials into dead Qb/Kb
  gemm_bt<4, 2><<<384, 256, 0, stream>>>(AO, WpT, MROWS, CDIM, CDIM,
                                         nullptr, nullptr, nullptr, partP,
                                         nullptr, nullptr, nullptr);
  // fused reduce + LN2: x1 = x + sum2 + bp ; h2 = LN(x1)
  redln<<<4096, 256, 0, stream>>>(partP, bp, x, x1, ln2g, ln2b, h2);
  // FF1 (+ReLU) -> a1 bf16
  gemm_bt<2><<<768, 256, 0, stream>>>(h2, W1T, MROWS, FDIM, CDIM,
                                      b1, nullptr, nullptr, a1, nullptr, nullptr, nullptr);
  // FF2 split-K=4: bf16 partials into dead [Qb..AO] region
  gemm_bt<4, 4><<<768, 256, 0, stream>>>(a1, W2T, MROWS, CDIM, FDIM,
                                         nullptr, nullptr, nullptr, partP,
                                         nullptr, nullptr, nullptr);
  // reduce: out = x1 + relu(sum4 + b2)
  reduce_k<4, true><<<3072, 256, 0, stream>>>(partP, b2, x1, out);
}